// Round 3
// baseline (147.263 us; speedup 1.0000x reference)
//
#include <hip/hip_runtime.h>
#include <hip/hip_bf16.h>

#define B_ 8
#define S_ 2048
#define E_ 1024
#define H_ 64

typedef __attribute__((ext_vector_type(8))) short short8;
typedef __attribute__((ext_vector_type(4))) float f32x4;

__device__ __forceinline__ unsigned short f2bf(float f) {
    unsigned int u = __float_as_uint(f);
    u = (u + 0x7FFFu + ((u >> 16) & 1u)) >> 16;
    return (unsigned short)u;
}

// Kernel 0: Wq/Wk/Wv [1024][64] f32 -> Wt bf16 [192][1024] (transposed, n-major).
// Coalesced reads: 64 consecutive lanes read 64 consecutive h of one k-row.
__global__ __launch_bounds__(256) void prep_weights(
    const float* __restrict__ Wq, const float* __restrict__ Wk,
    const float* __restrict__ Wv, unsigned short* __restrict__ Wt)
{
    int t = threadIdx.x;
    int k = blockIdx.x * 4 + (t >> 6);   // grid 256 -> k in [0,1024)
    int h = t & 63;
    float q = Wq[k * 64 + h];
    float kk = Wk[k * 64 + h];
    float v = Wv[k * 64 + h];
    Wt[(size_t)h * E_ + k] = f2bf(q);
    Wt[(size_t)(64 + h) * E_ + k] = f2bf(kk);
    Wt[(size_t)(128 + h) * E_ + k] = f2bf(v);
}

// Kernel 1: QKV projection, N-split across 4 waves, zero LDS.
// Block = 16 rows; wave w owns col-tiles nt = 3w..3w+2 (48 cols), full K=1024.
// All 4 waves read the same x rows in lockstep -> L1 serves the redundancy.
__global__ __launch_bounds__(256) void qkv_proj(
    const float* __restrict__ x, const float* __restrict__ bq,
    const float* __restrict__ bk, const float* __restrict__ bv,
    const unsigned short* __restrict__ Wt,
    unsigned short* __restrict__ Q, unsigned short* __restrict__ K,
    unsigned short* __restrict__ Vt)
{
    int tid = threadIdx.x;
    int wave = tid >> 6, lane = tid & 63;
    int lo = lane & 15, hi = lane >> 4;
    int rowbase = blockIdx.x * 16;

    f32x4 acc[3];
    #pragma unroll
    for (int i = 0; i < 3; ++i) acc[i] = (f32x4){0.f, 0.f, 0.f, 0.f};

    const float* xr = x + (size_t)(rowbase + lo) * E_ + 8 * hi;
    const unsigned short* wp = Wt + (size_t)(wave * 48 + lo) * E_ + 8 * hi;
    #pragma unroll 4
    for (int k0 = 0; k0 < E_; k0 += 32) {
        float4 a0 = *(const float4*)(xr + k0);
        float4 a1 = *(const float4*)(xr + k0 + 4);
        short8 af;
        af[0] = f2bf(a0.x); af[1] = f2bf(a0.y); af[2] = f2bf(a0.z); af[3] = f2bf(a0.w);
        af[4] = f2bf(a1.x); af[5] = f2bf(a1.y); af[6] = f2bf(a1.z); af[7] = f2bf(a1.w);
        #pragma unroll
        for (int j = 0; j < 3; ++j) {
            short8 bf = *(const short8*)(wp + (size_t)j * 16 * E_ + k0);
            acc[j] = __builtin_amdgcn_mfma_f32_16x16x32_bf16(af, bf, acc[j], 0, 0, 0);
        }
    }

    #pragma unroll
    for (int j = 0; j < 3; ++j) {
        int nt = wave * 3 + j;
        int n = nt * 16 + lo;
        #pragma unroll
        for (int r = 0; r < 4; ++r) {
            int row = rowbase + 4 * hi + r;   // global row in [0, 16384)
            float v = acc[j][r];
            if (nt < 4) {
                Q[(size_t)row * 64 + n] = f2bf(v + bq[n]);
            } else if (nt < 8) {
                int h = n - 64;
                K[(size_t)row * 64 + h] = f2bf(v + bk[h]);
            } else {
                int h = n - 128;
                int b = row >> 11, s = row & (S_ - 1);
                Vt[((size_t)b * 64 + h) * S_ + s] = f2bf(v + bv[h]);
            }
        }
    }
}

// Kernel 2: flash attention, KV-split across 4 waves.
// Block = one 16-row q-tile; wave w handles a contiguous chunk of 64-wide
// kv-tiles; partial (m,l,o) merged via LDS online-softmax combine.
__global__ __launch_bounds__(256) void attn(
    const unsigned short* __restrict__ Q, const unsigned short* __restrict__ K,
    const unsigned short* __restrict__ Vt, const int* __restrict__ mask,
    float* __restrict__ out)
{
    __shared__ __align__(16) unsigned short p_lds[4][16][72];  // 9 KB
    __shared__ float cm[4][64][25];                            // 25.6 KB (pad 24->25)
    int tid = threadIdx.x;
    int wave = tid >> 6, lane = tid & 63;
    int lo = lane & 15, hi = lane >> 4;
    int b = blockIdx.y;
    int qt = 127 - blockIdx.x;          // heavy (large qt) blocks first
    int qrow0 = qt * 16;

    const unsigned short* qp = Q + ((size_t)(b * S_ + qrow0 + lo)) * 64 + 8 * hi;
    short8 qf0 = *(const short8*)(qp);
    short8 qf1 = *(const short8*)(qp + 32);

    f32x4 o[4];
    float m[4], ls[4];
    #pragma unroll
    for (int i = 0; i < 4; ++i) {
        o[i] = (f32x4){0.f, 0.f, 0.f, 0.f};
        m[i] = -__builtin_inff();
        ls[i] = 0.f;
    }

    int nkt = (qrow0 + 16 + 63) >> 6;          // kv tiles needed for this q-tile
    int chunk = (nkt + 3) >> 2;
    int kt0 = wave * chunk;
    int kt1 = min(kt0 + chunk, nkt);

    for (int kt = kt0; kt < kt1; ++kt) {
        int kbase = kt * 64;
        f32x4 s[4];
        #pragma unroll
        for (int i = 0; i < 4; ++i) s[i] = (f32x4){0.f, 0.f, 0.f, 0.f};

        // S = Q K^T (16 q-rows x 64 k-pos)
        const unsigned short* kp = K + ((size_t)(b * S_ + kbase + lo)) * 64 + 8 * hi;
        #pragma unroll
        for (int nt = 0; nt < 4; ++nt) {
            short8 kf0 = *(const short8*)(kp + (size_t)nt * 16 * 64);
            short8 kf1 = *(const short8*)(kp + (size_t)nt * 16 * 64 + 32);
            s[nt] = __builtin_amdgcn_mfma_f32_16x16x32_bf16(qf0, kf0, s[nt], 0, 0, 0);
            s[nt] = __builtin_amdgcn_mfma_f32_16x16x32_bf16(qf1, kf1, s[nt], 0, 0, 0);
        }

        // masking (causal + pad), scale 1/sqrt(64)
        int mv[4];
        #pragma unroll
        for (int nt = 0; nt < 4; ++nt) mv[nt] = mask[b * S_ + kbase + nt * 16 + lo];
        float rmax[4];
        #pragma unroll
        for (int r = 0; r < 4; ++r) rmax[r] = -__builtin_inff();
        #pragma unroll
        for (int nt = 0; nt < 4; ++nt) {
            int kpos = kbase + nt * 16 + lo;
            #pragma unroll
            for (int r = 0; r < 4; ++r) {
                int qpos = qrow0 + 4 * hi + r;
                float v = s[nt][r] * 0.125f;
                bool ok = (mv[nt] != 0) && (kpos <= qpos);
                v = ok ? v : -__builtin_inff();
                s[nt][r] = v;
                rmax[r] = fmaxf(rmax[r], v);
            }
        }
        #pragma unroll
        for (int r = 0; r < 4; ++r) {
            rmax[r] = fmaxf(rmax[r], __shfl_xor(rmax[r], 1));
            rmax[r] = fmaxf(rmax[r], __shfl_xor(rmax[r], 2));
            rmax[r] = fmaxf(rmax[r], __shfl_xor(rmax[r], 4));
            rmax[r] = fmaxf(rmax[r], __shfl_xor(rmax[r], 8));
        }
        float mneff[4], sc[4];
        #pragma unroll
        for (int r = 0; r < 4; ++r) {
            float mn = fmaxf(m[r], rmax[r]);
            bool dead = (mn == -__builtin_inff());
            mneff[r] = dead ? 0.f : mn;
            sc[r] = __expf(m[r] - mneff[r]);
            m[r] = dead ? m[r] : mn;
        }
        float ps[4] = {0.f, 0.f, 0.f, 0.f};
        #pragma unroll
        for (int nt = 0; nt < 4; ++nt) {
            #pragma unroll
            for (int r = 0; r < 4; ++r) {
                float p = __expf(s[nt][r] - mneff[r]);
                ps[r] += p;
                p_lds[wave][4 * hi + r][nt * 16 + lo] = f2bf(p);
            }
        }
        #pragma unroll
        for (int r = 0; r < 4; ++r) {
            ps[r] += __shfl_xor(ps[r], 1);
            ps[r] += __shfl_xor(ps[r], 2);
            ps[r] += __shfl_xor(ps[r], 4);
            ps[r] += __shfl_xor(ps[r], 8);
            ls[r] = ls[r] * sc[r] + ps[r];
        }
        #pragma unroll
        for (int nt = 0; nt < 4; ++nt) {
            #pragma unroll
            for (int r = 0; r < 4; ++r) o[nt][r] *= sc[r];
        }

        // O += P V  (P via LDS round-trip to A-layout; V from transposed Vt)
        const unsigned short* vp = Vt + (size_t)b * 64 * S_ + kbase;
        #pragma unroll
        for (int kk = 0; kk < 2; ++kk) {
            short8 pf = *(const short8*)&p_lds[wave][lo][kk * 32 + 8 * hi];
            #pragma unroll
            for (int nt = 0; nt < 4; ++nt) {
                short8 vf = *(const short8*)(vp + (size_t)(nt * 16 + lo) * S_ + kk * 32 + 8 * hi);
                o[nt] = __builtin_amdgcn_mfma_f32_16x16x32_bf16(pf, vf, o[nt], 0, 0, 0);
            }
        }
    }

    // write partials: [0..3]=m, [4..7]=l, [8..23]=o
    #pragma unroll
    for (int r = 0; r < 4; ++r) {
        cm[wave][lane][r] = m[r];
        cm[wave][lane][4 + r] = ls[r];
    }
    #pragma unroll
    for (int nt = 0; nt < 4; ++nt)
        #pragma unroll
        for (int r = 0; r < 4; ++r)
            cm[wave][lane][8 + nt * 4 + r] = o[nt][r];
    __syncthreads();

    // combine: wave w produces output columns [w*16, w*16+16)
    #pragma unroll
    for (int r = 0; r < 4; ++r) {
        float mg = cm[0][lane][r];
        #pragma unroll
        for (int w2 = 1; w2 < 4; ++w2) mg = fmaxf(mg, cm[w2][lane][r]);
        float mge = (mg == -__builtin_inff()) ? 0.f : mg;
        float suml = 0.f, og = 0.f;
        #pragma unroll
        for (int w2 = 0; w2 < 4; ++w2) {
            float e = __expf(cm[w2][lane][r] - mge);
            suml += cm[w2][lane][4 + r] * e;
            og += cm[w2][lane][8 + wave * 4 + r] * e;
        }
        int qpos = qrow0 + 4 * hi + r;
        out[((size_t)(b * S_ + qpos)) * 64 + wave * 16 + lo] =
            (suml > 0.f) ? og / suml : 0.f;
    }
}

extern "C" void kernel_launch(void* const* d_in, const int* in_sizes, int n_in,
                              void* d_out, int out_size, void* d_ws, size_t ws_size,
                              hipStream_t stream) {
    const float* x   = (const float*)d_in[0];
    const int*   msk = (const int*)d_in[1];
    const float* Wq  = (const float*)d_in[2];
    const float* bq  = (const float*)d_in[3];
    const float* Wk  = (const float*)d_in[4];
    const float* bk  = (const float*)d_in[5];
    const float* Wv  = (const float*)d_in[6];
    const float* bv  = (const float*)d_in[7];
    float* out = (float*)d_out;

    // ws layout: Wt bf16 384KB @0 | Q bf16 2MB @512KB | K bf16 2MB | Vt bf16 2MB
    unsigned short* Wt = (unsigned short*)d_ws;
    unsigned short* Qb = (unsigned short*)((char*)d_ws + (1u << 19));
    unsigned short* Kb = (unsigned short*)((char*)d_ws + (1u << 19) + (1u << 21));
    unsigned short* Vt = (unsigned short*)((char*)d_ws + (1u << 19) + (2u << 21));

    prep_weights<<<dim3(256), dim3(256), 0, stream>>>(Wq, Wk, Wv, Wt);
    qkv_proj<<<dim3(1024), dim3(256), 0, stream>>>(x, bq, bk, bv, Wt, Qb, Kb, Vt);
    attn<<<dim3(128, 8), dim3(256), 0, stream>>>(Qb, Kb, Vt, msk, out);
}

// Round 4
// 116.129 us; speedup vs baseline: 1.2681x; 1.2681x over previous
//
#include <hip/hip_runtime.h>
#include <hip/hip_bf16.h>

#define B_ 8
#define S_ 2048
#define E_ 1024
#define H_ 64

typedef __attribute__((ext_vector_type(8))) short short8;
typedef __attribute__((ext_vector_type(4))) float f32x4;

__device__ __forceinline__ short f2bf(float f) {
    __hip_bfloat16 h = __float2bfloat16(f);   // RNE; compiler fuses pairs to v_cvt_pk_bf16_f32
    return *(short*)&h;
}

__device__ __forceinline__ void g2l16(const void* g, void* l) {
    __builtin_amdgcn_global_load_lds(
        (const __attribute__((address_space(1))) void*)g,
        (__attribute__((address_space(3))) void*)l, 16, 0, 0);
}

// Kernel 0: Wq/Wk/Wv [1024][64] f32 -> Wt bf16 [192][1024] (transposed, n-major).
// Coalesced writes (consecutive idx), strided reads served by L2.
__global__ __launch_bounds__(256) void prep_weights(
    const float* __restrict__ Wq, const float* __restrict__ Wk,
    const float* __restrict__ Wv, unsigned short* __restrict__ Wt)
{
    int idx = blockIdx.x * 256 + threadIdx.x;  // 192*1024 total
    int n = idx >> 10, k = idx & (E_ - 1);
    const float* W = (n < 64) ? Wq : (n < 128) ? Wk : Wv;
    int h = n & 63;
    Wt[idx] = (unsigned short)f2bf(W[k * 64 + h]);
}

// Kernel 1: QKV projection, global_load_lds double-buffered pipeline.
// Block = 512 thr (8 waves), M-tile 32 rows, K-chunk 256 f32 (1KB/row),
// LDS 2 x 32KB. Wave (wm,wn): rows wm*16..+16, cols wn*48..+48.
// x staged with per-row XOR swizzle (row&7)<<4 on 16B units (source-side).
__global__ __launch_bounds__(512) void qkv_proj(
    const float* __restrict__ x, const float* __restrict__ bq,
    const float* __restrict__ bk, const float* __restrict__ bv,
    const unsigned short* __restrict__ Wt,
    unsigned short* __restrict__ Q, unsigned short* __restrict__ K,
    unsigned short* __restrict__ Vt)
{
    __shared__ __align__(16) char lds[2][32 * 1024];
    int tid = threadIdx.x;
    int wave = tid >> 6, lane = tid & 63;
    int lo = lane & 15, hi = lane >> 4;
    int wm = wave >> 2, wn = wave & 3;
    int rowbase = blockIdx.x * 32;

    const char* xbase = (const char*)(x + (size_t)rowbase * E_);

    f32x4 acc[3];
    #pragma unroll
    for (int i = 0; i < 3; ++i) acc[i] = (f32x4){0.f, 0.f, 0.f, 0.f};

    int swz = (lo & 7) << 4;
    const unsigned short* wp = Wt + (size_t)(wn * 48 + lo) * E_ + 8 * hi;

    // stage chunk kc into buffer bb: 32 rows x 1KB, wave issues rows i*8+wave
    #define STAGE(bb, kc)                                                        \
        {                                                                        \
            _Pragma("unroll")                                                    \
            for (int i = 0; i < 4; ++i) {                                        \
                int r = i * 8 + wave;                                            \
                const char* src = xbase + (size_t)r * 4096 + (kc) * 1024         \
                                  + ((lane * 16) ^ ((r & 7) << 4));              \
                g2l16(src, &lds[bb][r * 1024]);                                  \
            }                                                                    \
        }

    STAGE(0, 0);
    __syncthreads();

    for (int kc = 0; kc < 4; ++kc) {
        if (kc < 3) STAGE((kc + 1) & 1, kc + 1);
        const char* lb = lds[kc & 1] + (wm * 16 + lo) * 1024;
        #pragma unroll
        for (int sub = 0; sub < 8; ++sub) {
            int off = ((sub * 128 + hi * 32) ^ swz);
            float4 a0 = *(const float4*)(lb + off);
            float4 a1 = *(const float4*)(lb + (off ^ 16));
            short8 af;
            af[0] = f2bf(a0.x); af[1] = f2bf(a0.y); af[2] = f2bf(a0.z); af[3] = f2bf(a0.w);
            af[4] = f2bf(a1.x); af[5] = f2bf(a1.y); af[6] = f2bf(a1.z); af[7] = f2bf(a1.w);
            int k0 = kc * 256 + sub * 32;
            #pragma unroll
            for (int j = 0; j < 3; ++j) {
                short8 bf = *(const short8*)(wp + (size_t)j * 16 * E_ + k0);
                acc[j] = __builtin_amdgcn_mfma_f32_16x16x32_bf16(af, bf, acc[j], 0, 0, 0);
            }
        }
        __syncthreads();
    }

    #pragma unroll
    for (int j = 0; j < 3; ++j) {
        int nt = wn * 3 + j;
        int n = nt * 16 + lo;
        #pragma unroll
        for (int r = 0; r < 4; ++r) {
            int row = rowbase + wm * 16 + 4 * hi + r;   // [0, 16384)
            float v = acc[j][r];
            if (nt < 4) {
                Q[(size_t)row * 64 + n] = (unsigned short)f2bf(v + bq[n]);
            } else if (nt < 8) {
                int h = n - 64;
                K[(size_t)row * 64 + h] = (unsigned short)f2bf(v + bk[h]);
            } else {
                int h = n - 128;
                int b = row >> 11, s = row & (S_ - 1);
                Vt[((size_t)b * 64 + h) * S_ + s] = (unsigned short)f2bf(v + bv[h]);
            }
        }
    }
    #undef STAGE
}

// Kernel 2: flash attention, KV-split across 4 waves.
// Block = one 16-row q-tile; wave w handles a contiguous chunk of 64-wide
// kv-tiles; partial (m,l,o) merged via LDS online-softmax combine.
__global__ __launch_bounds__(256) void attn(
    const unsigned short* __restrict__ Q, const unsigned short* __restrict__ K,
    const unsigned short* __restrict__ Vt, const int* __restrict__ mask,
    float* __restrict__ out)
{
    __shared__ __align__(16) unsigned short p_lds[4][16][72];  // 9 KB
    __shared__ float cm[4][64][25];                            // 25.6 KB
    int tid = threadIdx.x;
    int wave = tid >> 6, lane = tid & 63;
    int lo = lane & 15, hi = lane >> 4;
    int b = blockIdx.y;
    int qt = 127 - blockIdx.x;          // heavy (large qt) blocks first
    int qrow0 = qt * 16;

    const unsigned short* qp = Q + ((size_t)(b * S_ + qrow0 + lo)) * 64 + 8 * hi;
    short8 qf0 = *(const short8*)(qp);
    short8 qf1 = *(const short8*)(qp + 32);

    f32x4 o[4];
    float m[4], ls[4];
    #pragma unroll
    for (int i = 0; i < 4; ++i) {
        o[i] = (f32x4){0.f, 0.f, 0.f, 0.f};
        m[i] = -__builtin_inff();
        ls[i] = 0.f;
    }

    int nkt = (qrow0 + 16 + 63) >> 6;          // kv tiles needed for this q-tile
    int chunk = (nkt + 3) >> 2;
    int kt0 = wave * chunk;
    int kt1 = min(kt0 + chunk, nkt);

    for (int kt = kt0; kt < kt1; ++kt) {
        int kbase = kt * 64;

        // prefetch mask + first-half V fragments (independent of QK chain)
        int mv[4];
        #pragma unroll
        for (int nt = 0; nt < 4; ++nt) mv[nt] = mask[b * S_ + kbase + nt * 16 + lo];
        const unsigned short* vp = Vt + (size_t)b * 64 * S_ + kbase;
        short8 vf0[4];
        #pragma unroll
        for (int nt = 0; nt < 4; ++nt)
            vf0[nt] = *(const short8*)(vp + (size_t)(nt * 16 + lo) * S_ + 8 * hi);

        f32x4 s[4];
        #pragma unroll
        for (int i = 0; i < 4; ++i) s[i] = (f32x4){0.f, 0.f, 0.f, 0.f};

        // S = Q K^T (16 q-rows x 64 k-pos)
        const unsigned short* kp = K + ((size_t)(b * S_ + kbase + lo)) * 64 + 8 * hi;
        #pragma unroll
        for (int nt = 0; nt < 4; ++nt) {
            short8 kf0 = *(const short8*)(kp + (size_t)nt * 16 * 64);
            short8 kf1 = *(const short8*)(kp + (size_t)nt * 16 * 64 + 32);
            s[nt] = __builtin_amdgcn_mfma_f32_16x16x32_bf16(qf0, kf0, s[nt], 0, 0, 0);
            s[nt] = __builtin_amdgcn_mfma_f32_16x16x32_bf16(qf1, kf1, s[nt], 0, 0, 0);
        }

        // masking (causal + pad), scale 1/sqrt(64)
        float rmax[4];
        #pragma unroll
        for (int r = 0; r < 4; ++r) rmax[r] = -__builtin_inff();
        #pragma unroll
        for (int nt = 0; nt < 4; ++nt) {
            int kpos = kbase + nt * 16 + lo;
            #pragma unroll
            for (int r = 0; r < 4; ++r) {
                int qpos = qrow0 + 4 * hi + r;
                float v = s[nt][r] * 0.125f;
                bool ok = (mv[nt] != 0) && (kpos <= qpos);
                v = ok ? v : -__builtin_inff();
                s[nt][r] = v;
                rmax[r] = fmaxf(rmax[r], v);
            }
        }
        #pragma unroll
        for (int r = 0; r < 4; ++r) {
            rmax[r] = fmaxf(rmax[r], __shfl_xor(rmax[r], 1));
            rmax[r] = fmaxf(rmax[r], __shfl_xor(rmax[r], 2));
            rmax[r] = fmaxf(rmax[r], __shfl_xor(rmax[r], 4));
            rmax[r] = fmaxf(rmax[r], __shfl_xor(rmax[r], 8));
        }
        float mneff[4], sc[4];
        #pragma unroll
        for (int r = 0; r < 4; ++r) {
            float mn = fmaxf(m[r], rmax[r]);
            bool dead = (mn == -__builtin_inff());
            mneff[r] = dead ? 0.f : mn;
            sc[r] = __expf(m[r] - mneff[r]);
            m[r] = dead ? m[r] : mn;
        }
        float ps[4] = {0.f, 0.f, 0.f, 0.f};
        #pragma unroll
        for (int nt = 0; nt < 4; ++nt) {
            #pragma unroll
            for (int r = 0; r < 4; ++r) {
                float p = __expf(s[nt][r] - mneff[r]);
                ps[r] += p;
                p_lds[wave][4 * hi + r][nt * 16 + lo] = (unsigned short)f2bf(p);
            }
        }
        #pragma unroll
        for (int r = 0; r < 4; ++r) {
            ps[r] += __shfl_xor(ps[r], 1);
            ps[r] += __shfl_xor(ps[r], 2);
            ps[r] += __shfl_xor(ps[r], 4);
            ps[r] += __shfl_xor(ps[r], 8);
            ls[r] = ls[r] * sc[r] + ps[r];
        }
        #pragma unroll
        for (int nt = 0; nt < 4; ++nt) {
            #pragma unroll
            for (int r = 0; r < 4; ++r) o[nt][r] *= sc[r];
        }

        // O += P V  (P via LDS round-trip to A-layout; V from transposed Vt)
        {
            short8 pf = *(const short8*)&p_lds[wave][lo][8 * hi];
            #pragma unroll
            for (int nt = 0; nt < 4; ++nt)
                o[nt] = __builtin_amdgcn_mfma_f32_16x16x32_bf16(pf, vf0[nt], o[nt], 0, 0, 0);
        }
        {
            short8 pf = *(const short8*)&p_lds[wave][lo][32 + 8 * hi];
            #pragma unroll
            for (int nt = 0; nt < 4; ++nt) {
                short8 vf = *(const short8*)(vp + (size_t)(nt * 16 + lo) * S_ + 32 + 8 * hi);
                o[nt] = __builtin_amdgcn_mfma_f32_16x16x32_bf16(pf, vf, o[nt], 0, 0, 0);
            }
        }
    }

    // write partials: [0..3]=m, [4..7]=l, [8..23]=o
    #pragma unroll
    for (int r = 0; r < 4; ++r) {
        cm[wave][lane][r] = m[r];
        cm[wave][lane][4 + r] = ls[r];
    }
    #pragma unroll
    for (int nt = 0; nt < 4; ++nt)
        #pragma unroll
        for (int r = 0; r < 4; ++r)
            cm[wave][lane][8 + nt * 4 + r] = o[nt][r];
    __syncthreads();

    // combine: wave w produces output columns [w*16, w*16+16)
    #pragma unroll
    for (int r = 0; r < 4; ++r) {
        float mg = cm[0][lane][r];
        #pragma unroll
        for (int w2 = 1; w2 < 4; ++w2) mg = fmaxf(mg, cm[w2][lane][r]);
        float mge = (mg == -__builtin_inff()) ? 0.f : mg;
        float suml = 0.f, og = 0.f;
        #pragma unroll
        for (int w2 = 0; w2 < 4; ++w2) {
            float e = __expf(cm[w2][lane][r] - mge);
            suml += cm[w2][lane][4 + r] * e;
            og += cm[w2][lane][8 + wave * 4 + r] * e;
        }
        int qpos = qrow0 + 4 * hi + r;
        out[((size_t)(b * S_ + qpos)) * 64 + wave * 16 + lo] =
            (suml > 0.f) ? og / suml : 0.f;
    }
}

extern "C" void kernel_launch(void* const* d_in, const int* in_sizes, int n_in,
                              void* d_out, int out_size, void* d_ws, size_t ws_size,
                              hipStream_t stream) {
    const float* x   = (const float*)d_in[0];
    const int*   msk = (const int*)d_in[1];
    const float* Wq  = (const float*)d_in[2];
    const float* bq  = (const float*)d_in[3];
    const float* Wk  = (const float*)d_in[4];
    const float* bk  = (const float*)d_in[5];
    const float* Wv  = (const float*)d_in[6];
    const float* bv  = (const float*)d_in[7];
    float* out = (float*)d_out;

    // ws layout: Wt bf16 384KB @0 | Q bf16 2MB @512KB | K bf16 2MB | Vt bf16 2MB
    unsigned short* Wt = (unsigned short*)d_ws;
    unsigned short* Qb = (unsigned short*)((char*)d_ws + (1u << 19));
    unsigned short* Kb = (unsigned short*)((char*)d_ws + (1u << 19) + (1u << 21));
    unsigned short* Vt = (unsigned short*)((char*)d_ws + (1u << 19) + (2u << 21));

    prep_weights<<<dim3(768), dim3(256), 0, stream>>>(Wq, Wk, Wv, Wt);
    qkv_proj<<<dim3(512), dim3(512), 0, stream>>>(x, bq, bk, bv, Wt, Qb, Kb, Vt);
    attn<<<dim3(128, 8), dim3(256), 0, stream>>>(Qb, Kb, Vt, msk, out);
}